// Round 17
// baseline (448.843 us; speedup 1.0000x reference)
//
#include <hip/hip_runtime.h>
#include <hip/hip_bf16.h>

#define B_ 2
#define S_ 2048
#define D_ 1024
#define H_ 16
#define HD_ 64

typedef __attribute__((ext_vector_type(8))) short short8;
typedef __attribute__((ext_vector_type(4))) short short4v;
typedef __attribute__((ext_vector_type(4))) float float4v;

typedef const __attribute__((address_space(1))) void* gas_ptr;
typedef __attribute__((address_space(3))) void* las_ptr;

static __device__ inline void gl_lds16(const void* g, void* l) {
  __builtin_amdgcn_global_load_lds((gas_ptr)g, (las_ptr)l, 16, 0, 0);
}

static __device__ inline float b2f(__hip_bfloat16 h) { return __bfloat162float(h); }

static __device__ inline short f2bs(float x) {
  __hip_bfloat16 h = __float2bfloat16(x);
  union { __hip_bfloat16 h; short s; } u; u.h = h; return u.s;
}
static __device__ inline float bs2f(short s) {
  union { short s; __hip_bfloat16 h; } u; u.s = s; return __bfloat162float(u.h);
}
// packed f32x4 -> bf16x4 (v_cvt_pk_bf16_f32 x2)
static __device__ inline short4v pk4(float a, float b, float c, float d) {
  union { __hip_bfloat162 h[2]; short4v s; } u;
  u.h[0] = __float22bfloat162_rn(float2{a, b});
  u.h[1] = __float22bfloat162_rn(float2{c, d});
  return u.s;
}

static __device__ inline float4v mfma32(short8 a, short8 b, float4v c) {
  return __builtin_amdgcn_mfma_f32_16x16x32_bf16(a, b, c, 0, 0, 0);
}
// v_mfma_f32_16x16x16_bf16 — "_1k" builtin, present on gfx950.
static __device__ inline float4v mfma16(short4v a, short4v b, float4v c) {
  return __builtin_amdgcn_mfma_f32_16x16x16bf16_1k(a, b, c, 0, 0, 0);
}

// ------- Stage A (fused): z<2 -> W transpose fp32->bf16; z==2 -> hs cvt -------
__global__ __launch_bounds__(256) void pre(
    const float* __restrict__ Wq, const float* __restrict__ Wk,
    const float* __restrict__ hs,
    __hip_bfloat16* __restrict__ Wqt, __hip_bfloat16* __restrict__ Wkt,
    __hip_bfloat16* __restrict__ hsb) {
  if (blockIdx.z == 2) {
    const int blk = blockIdx.y * 16 + blockIdx.x;
    for (int it = 0; it < 8; ++it) {
      const size_t i = (size_t)blk * 16384 + it * 2048 + threadIdx.x * 8;
      const float4v v0 = *(const float4v*)(hs + i);
      const float4v v1 = *(const float4v*)(hs + i + 4);
      short8 s;
      for (int j = 0; j < 4; ++j) { s[j] = f2bs(v0[j]); s[4 + j] = f2bs(v1[j]); }
      *(short8*)(hsb + i) = s;
    }
    return;
  }
  const float* W = blockIdx.z ? Wk : Wq;
  __hip_bfloat16* Wt = blockIdx.z ? Wkt : Wqt;
  __shared__ float t[64][65];
  const int n0 = blockIdx.x * 64, k0 = blockIdx.y * 64;
  const int c = threadIdx.x & 63, r0 = threadIdx.x >> 6;
  for (int i = 0; i < 16; ++i) {
    const int r = i * 4 + r0;
    t[c][r] = W[(size_t)(k0 + r) * D_ + n0 + c];
  }
  __syncthreads();
  for (int i = 0; i < 16; ++i) {
    const int rr = i * 4 + r0;
    Wt[(size_t)(n0 + rr) * D_ + k0 + c] = __float2bfloat16(t[rr][c]);
  }
}

// ---- Stage B (fused GEMM+prep): 128x128 tile, 512 thr / 8 waves (m97-class).
// Computes q-tile AND k-tile of the same range; epilogue emits q, kt=softplus(k),
// vT[b,h,d,p(s)] = q+k (key-swizzled per 64-chunk for attn's b128 PV loads).
__global__ __launch_bounds__(512, 2) void gemm_fused(
    const __hip_bfloat16* __restrict__ A,
    const __hip_bfloat16* __restrict__ Wqt, const __hip_bfloat16* __restrict__ Wkt,
    const float* __restrict__ bq, const float* __restrict__ bk,
    __hip_bfloat16* __restrict__ q_out, __hip_bfloat16* __restrict__ kt_out,
    __hip_bfloat16* __restrict__ vT) {
  const int n0 = blockIdx.x * 128, m0 = blockIdx.y * 128;
  __shared__ __hip_bfloat16 As[2][128 * 32];
  __shared__ __hip_bfloat16 Bq[2][128 * 32];
  __shared__ __hip_bfloat16 Bk[2][128 * 32];
  const int tid = threadIdx.x, wid = tid >> 6, lane = tid & 63;
  const int wm = (wid >> 1) * 32, wn = (wid & 1) * 64;
  const int l15 = lane & 15, l4 = lane >> 4;
  const float4v zz = {0.f, 0.f, 0.f, 0.f};
  float4v accq[2][4], acck[2][4];
  for (int i = 0; i < 2; ++i)
    for (int j = 0; j < 4; ++j) { accq[i][j] = zz; acck[i][j] = zz; }
  const int lrow = wid * 16 + (lane >> 2);
  const int lk8 = (lane & 3) * 8;
  gl_lds16(A + (size_t)(m0 + lrow) * D_ + lk8, As[0] + wid * 512);
  gl_lds16(Wqt + (size_t)(n0 + lrow) * D_ + lk8, Bq[0] + wid * 512);
  gl_lds16(Wkt + (size_t)(n0 + lrow) * D_ + lk8, Bk[0] + wid * 512);
  int p = 0;
  for (int kb = 0; kb < 32; ++kb) {
    __syncthreads();
    if (kb < 31) {
      const int kc = (kb + 1) * 32 + lk8;
      gl_lds16(A + (size_t)(m0 + lrow) * D_ + kc, As[p ^ 1] + wid * 512);
      gl_lds16(Wqt + (size_t)(n0 + lrow) * D_ + kc, Bq[p ^ 1] + wid * 512);
      gl_lds16(Wkt + (size_t)(n0 + lrow) * D_ + kc, Bk[p ^ 1] + wid * 512);
    }
    short8 af[2], bfq[4], bfk[4];
    const int fo = l4 * 8;
    for (int rt = 0; rt < 2; ++rt)
      af[rt] = *(const short8*)(As[p] + (wm + rt * 16 + l15) * 32 + fo);
    for (int ct = 0; ct < 4; ++ct) {
      bfq[ct] = *(const short8*)(Bq[p] + (wn + ct * 16 + l15) * 32 + fo);
      bfk[ct] = *(const short8*)(Bk[p] + (wn + ct * 16 + l15) * 32 + fo);
    }
    for (int rt = 0; rt < 2; ++rt)
      for (int ct = 0; ct < 4; ++ct) {
        accq[rt][ct] = mfma32(af[rt], bfq[ct], accq[rt][ct]);
        acck[rt][ct] = mfma32(af[rt], bfk[ct], acck[rt][ct]);
      }
    p ^= 1;
  }
  float bvq[4], bvk[4];
  for (int ct = 0; ct < 4; ++ct) {
    bvq[ct] = bq[n0 + wn + ct * 16 + l15];
    bvk[ct] = bk[n0 + wn + ct * 16 + l15];
  }
  for (int rt = 0; rt < 2; ++rt)
    for (int ct = 0; ct < 4; ++ct) {
      const int col = n0 + wn + ct * 16 + l15;
      const int h = col >> 6, d = col & 63;
      const int rowb = m0 + wm + rt * 16 + l4 * 4;
      short4v vv;
      for (int r = 0; r < 4; ++r) {
        const int row = rowb + r;
        const float qv = accq[rt][ct][r] + bvq[ct];
        const float kv = acck[rt][ct][r] + bvk[ct];
        const float sp = fmaxf(kv, 0.f) + __logf(1.f + __expf(-fabsf(kv)));
        q_out[(size_t)row * D_ + col] = __float2bfloat16(qv);
        kt_out[(size_t)row * D_ + col] = __float2bfloat16(sp);
        vv[r] = f2bs(qv + kv);
      }
      const int b = rowb >> 11, s = rowb & 2047;
      // key swizzle p(k) within 64-chunk; s%4==0 -> 4 consecutive stay together
      const int sw = (s & ~63) | (((s >> 4) & 3) << 2) | (((s >> 2) & 3) << 4);
      *(short4v*)(vT + ((size_t)(b * H_ + h) * HD_ + d) * S_ + sw) = vv;
    }
}

// ------- Stage D: flash attention — XCD-pinned, DIRECT-FROM-L2 (no LDS loop) ----
// Grid 512: xcd=id&7; q0=((id>>3)&15)*128; hb=(id>>7)*8+xcd. kt/v slice of each
// (b,h) is L2-resident on its XCD (r14: FETCH 12.6 MB), so fragments are read
// straight from global/L2 — NO staging, NO in-loop LDS, NO barriers; waves
// free-run with a register double-buffer (16x short8). 256 thr = 4 waves; wave
// owns 32 queries (2 MFMA tiles A/B). V is producer-key-swizzled -> PV frags
// are contiguous b128 loads. LDS used only for the epilogue transpose.
__global__ __launch_bounds__(256, 2) void attn(
    const __hip_bfloat16* __restrict__ qb, const __hip_bfloat16* __restrict__ ktb,
    const __hip_bfloat16* __restrict__ vT, const int* __restrict__ mask,
    float* __restrict__ out) {
  __shared__ float mbuf[128 * 68 + 128];  // epilogue only: 35.3 KB
  const int id = blockIdx.x;
  const int xcd = id & 7;
  const int q0 = ((id >> 3) & 15) * 128;
  const int hb = (id >> 7) * 8 + xcd;  // 0..31
  const int h = hb >> 1, b = hb & 1;
  const int tid = threadIdx.x, wid = tid >> 6, lane = tid & 63;
  const int l15 = lane & 15, l4 = lane >> 4;
  const __hip_bfloat16* qh = qb + (size_t)b * S_ * D_ + h * HD_;
  const __hip_bfloat16* kh = ktb + (size_t)b * S_ * D_ + h * HD_;
  const __hip_bfloat16* vh = vT + (size_t)(b * H_ + h) * HD_ * S_;

  // q B-fragments for tiles A,B; mask*scale*log2e folded in
  const int qlA = wid * 32 + l15, qlB = qlA + 16;
  const int qrA = q0 + qlA, qrB = q0 + qlB;
  const float SC = 0.125f * 1.44269504f;
  const float mqA = (mask[b * S_ + qrA] != 0) ? SC : 0.f;
  const float mqB = (mask[b * S_ + qrB] != 0) ? SC : 0.f;
  const short8 rA0 = *(const short8*)(qh + (size_t)qrA * D_ + l4 * 8);
  const short8 rA1 = *(const short8*)(qh + (size_t)qrA * D_ + 32 + l4 * 8);
  const short8 rB0 = *(const short8*)(qh + (size_t)qrB * D_ + l4 * 8);
  const short8 rB1 = *(const short8*)(qh + (size_t)qrB * D_ + 32 + l4 * 8);
  short8 bqA0, bqA1, bqB0, bqB1;
  for (int j = 0; j < 8; ++j) {
    bqA0[j] = f2bs(bs2f(rA0[j]) * mqA);
    bqA1[j] = f2bs(bs2f(rA1[j]) * mqA);
    bqB0[j] = f2bs(bs2f(rB0[j]) * mqB);
    bqB1[j] = f2bs(bs2f(rB1[j]) * mqB);
  }

  // per-wave global fragment pointers (advance by 64 keys per chunk)
  const __hip_bfloat16* kp[4];  // kt row t*16+l15, cols {l4*8, 32+l4*8}
#pragma unroll
  for (int t = 0; t < 4; ++t) kp[t] = kh + (size_t)(t * 16 + l15) * D_ + l4 * 8;
  const __hip_bfloat16* vp[4];  // v row dt*16+l15, swizzled col l4*16 {+0,+8}
#pragma unroll
  for (int dt = 0; dt < 4; ++dt) vp[dt] = vh + (size_t)(dt * 16 + l15) * S_ + l4 * 16;

  const float4v zz = {0.f, 0.f, 0.f, 0.f};
  float4v oaccA[4] = {zz, zz, zz, zz};
  float4v oaccB[4] = {zz, zz, zz, zz};
  float lsumA = 0.f, lsumB = 0.f;

  // register double-buffer: kf[s][2t,2t+1], vf[s][2dt,2dt+1]
  short8 kf[2][8], vf[2][8];
#pragma unroll
  for (int t = 0; t < 4; ++t) {
    kf[0][2 * t] = *(const short8*)(kp[t]);
    kf[0][2 * t + 1] = *(const short8*)(kp[t] + 32);
    vf[0][2 * t] = *(const short8*)(vp[t]);
    vf[0][2 * t + 1] = *(const short8*)(vp[t] + 8);
  }

  for (int c = 0; c < 32; ++c) {
    const int s = c & 1, sn = s ^ 1;
    if (c < 31) {  // prefetch next chunk into the other reg set
      const int kb = (c + 1) * 64;
#pragma unroll
      for (int t = 0; t < 4; ++t) {
        kf[sn][2 * t] = *(const short8*)(kp[t] + (size_t)kb * D_);
        kf[sn][2 * t + 1] = *(const short8*)(kp[t] + (size_t)kb * D_ + 32);
        vf[sn][2 * t] = *(const short8*)(vp[t] + kb);
        vf[sn][2 * t + 1] = *(const short8*)(vp[t] + kb + 8);
      }
    }
    // ---- QK for 4 key-tiles -> P fragments (exp2 domain) ----
    short4v pA[4], pB[4];
#pragma unroll
    for (int t = 0; t < 4; ++t) {
      const short8 ak0 = kf[s][2 * t];
      const short8 ak1 = kf[s][2 * t + 1];
      float4v cA = zz, cB = zz;
      cA = mfma32(ak0, bqA0, cA);
      cA = mfma32(ak1, bqA1, cA);
      cB = mfma32(ak0, bqB0, cB);
      cB = mfma32(ak1, bqB1, cB);
      float eA[4], eB[4];
#pragma unroll
      for (int r = 0; r < 4; ++r) {
        eA[r] = __builtin_amdgcn_exp2f(cA[r]); lsumA += eA[r];
        eB[r] = __builtin_amdgcn_exp2f(cB[r]); lsumB += eB[r];
      }
      pA[t] = pk4(eA[0], eA[1], eA[2], eA[3]);
      pB[t] = pk4(eB[0], eB[1], eB[2], eB[3]);
    }
    // ---- PV; vf pairs cover all 4 key-tiles (producer swizzle) ----
#pragma unroll
    for (int dt = 0; dt < 4; ++dt) {
      const short8 av0 = vf[s][2 * dt];
      const short8 av1 = vf[s][2 * dt + 1];
      const short4v a0 = {av0[0], av0[1], av0[2], av0[3]};
      const short4v a1 = {av0[4], av0[5], av0[6], av0[7]};
      const short4v a2 = {av1[0], av1[1], av1[2], av1[3]};
      const short4v a3 = {av1[4], av1[5], av1[6], av1[7]};
      oaccA[dt] = mfma16(a0, pA[0], oaccA[dt]);
      oaccB[dt] = mfma16(a0, pB[0], oaccB[dt]);
      oaccA[dt] = mfma16(a1, pA[1], oaccA[dt]);
      oaccB[dt] = mfma16(a1, pB[1], oaccB[dt]);
      oaccA[dt] = mfma16(a2, pA[2], oaccA[dt]);
      oaccB[dt] = mfma16(a2, pB[2], oaccB[dt]);
      oaccA[dt] = mfma16(a3, pA[3], oaccA[dt]);
      oaccB[dt] = mfma16(a3, pB[3], oaccB[dt]);
    }
  }
  // ---- epilogue: quad-reduce l; LDS transpose for coalesced stores ----
  float lA = lsumA + __shfl_xor(lsumA, 16); lA += __shfl_xor(lA, 32);
  float lB = lsumB + __shfl_xor(lsumB, 16); lB += __shfl_xor(lB, 32);
  float* mlb = mbuf + 128 * 68;
#pragma unroll
  for (int dt = 0; dt < 4; ++dt)
#pragma unroll
    for (int r = 0; r < 4; ++r) {
      mbuf[qlA * 68 + dt * 16 + l4 * 4 + r] = oaccA[dt][r];
      mbuf[qlB * 68 + dt * 16 + l4 * 4 + r] = oaccB[dt][r];
    }
  if (l4 == 0) { mlb[qlA] = lA; mlb[qlB] = lB; }
  __syncthreads();
  const int qq = tid >> 1;            // query-local 0..127
  const int dg = (tid & 1) * 32;      // dim group
  const float li = 1.f / mlb[qq];
  float* orow = out + (size_t)(b * S_ + q0 + qq) * D_ + h * HD_ + dg;
#pragma unroll
  for (int i = 0; i < 8; ++i) {
    float4v v = *(const float4v*)&mbuf[qq * 68 + dg + i * 4];
#pragma unroll
    for (int r = 0; r < 4; ++r) v[r] *= li;
    *(float4v*)(orow + i * 4) = v;
  }
}

extern "C" void kernel_launch(void* const* d_in, const int* in_sizes, int n_in,
                              void* d_out, int out_size, void* d_ws, size_t ws_size,
                              hipStream_t stream) {
  const float* hs = (const float*)d_in[0];
  const int* mask = (const int*)d_in[1];
  const float* Wq = (const float*)d_in[2];
  const float* bq = (const float*)d_in[3];
  const float* Wk = (const float*)d_in[4];
  const float* bk = (const float*)d_in[5];
  float* out = (float*)d_out;
  char* ws = (char*)d_ws;
  const size_t MB = 1u << 20;
  __hip_bfloat16* q_b = (__hip_bfloat16*)(ws + 0 * MB);   // [B,S,D] bf16, 8MB
  __hip_bfloat16* k_b = (__hip_bfloat16*)(ws + 8 * MB);   // softplus(k), 8MB
  __hip_bfloat16* hsb = (__hip_bfloat16*)(ws + 16 * MB);  // hs bf16, 8MB
  __hip_bfloat16* vT  = (__hip_bfloat16*)(ws + 24 * MB);  // [B,H,HD,S] key-swizzled, 8MB
  __hip_bfloat16* Wqt = (__hip_bfloat16*)(ws + 32 * MB);  // 2MB
  __hip_bfloat16* Wkt = (__hip_bfloat16*)(ws + 34 * MB);  // 2MB

  pre<<<dim3(16, 16, 3), 256, 0, stream>>>(Wq, Wk, hs, Wqt, Wkt, hsb);
  gemm_fused<<<dim3(8, 32), 512, 0, stream>>>(hsb, Wqt, Wkt, bq, bk, q_b, k_b, vT);
  attn<<<dim3(512), 256, 0, stream>>>(q_b, k_b, vT, mask, out);
}

// Round 18
// 166.898 us; speedup vs baseline: 2.6893x; 2.6893x over previous
//
#include <hip/hip_runtime.h>
#include <hip/hip_bf16.h>

#define B_ 2
#define S_ 2048
#define D_ 1024
#define H_ 16
#define HD_ 64

typedef __attribute__((ext_vector_type(8))) short short8;
typedef __attribute__((ext_vector_type(4))) short short4v;
typedef __attribute__((ext_vector_type(4))) float float4v;

typedef const __attribute__((address_space(1))) void* gas_ptr;
typedef __attribute__((address_space(3))) void* las_ptr;

static __device__ inline void gl_lds16(const void* g, void* l) {
  __builtin_amdgcn_global_load_lds((gas_ptr)g, (las_ptr)l, 16, 0, 0);
}

static __device__ inline float b2f(__hip_bfloat16 h) { return __bfloat162float(h); }

static __device__ inline short f2bs(float x) {
  __hip_bfloat16 h = __float2bfloat16(x);
  union { __hip_bfloat16 h; short s; } u; u.h = h; return u.s;
}
static __device__ inline float bs2f(short s) {
  union { short s; __hip_bfloat16 h; } u; u.s = s; return __bfloat162float(u.h);
}
// packed f32x4 -> bf16x4 (v_cvt_pk_bf16_f32 x2)
static __device__ inline short4v pk4(float a, float b, float c, float d) {
  union { __hip_bfloat162 h[2]; short4v s; } u;
  u.h[0] = __float22bfloat162_rn(float2{a, b});
  u.h[1] = __float22bfloat162_rn(float2{c, d});
  return u.s;
}

static __device__ inline float4v mfma32(short8 a, short8 b, float4v c) {
  return __builtin_amdgcn_mfma_f32_16x16x32_bf16(a, b, c, 0, 0, 0);
}
// v_mfma_f32_16x16x16_bf16 — "_1k" builtin, present on gfx950.
static __device__ inline float4v mfma16(short4v a, short4v b, float4v c) {
  return __builtin_amdgcn_mfma_f32_16x16x16bf16_1k(a, b, c, 0, 0, 0);
}

// ------- Stage A: W fp32 [k][n] -> Wt bf16 [n][k] (hs cvt now fused in gemm) ---
__global__ __launch_bounds__(256) void pre(
    const float* __restrict__ Wq, const float* __restrict__ Wk,
    __hip_bfloat16* __restrict__ Wqt, __hip_bfloat16* __restrict__ Wkt) {
  const float* W = blockIdx.z ? Wk : Wq;
  __hip_bfloat16* Wt = blockIdx.z ? Wkt : Wqt;
  __shared__ float t[64][65];
  const int n0 = blockIdx.x * 64, k0 = blockIdx.y * 64;
  const int c = threadIdx.x & 63, r0 = threadIdx.x >> 6;
  for (int i = 0; i < 16; ++i) {
    const int r = i * 4 + r0;
    t[c][r] = W[(size_t)(k0 + r) * D_ + n0 + c];
  }
  __syncthreads();
  for (int i = 0; i < 16; ++i) {
    const int rr = i * 4 + r0;
    Wt[(size_t)(n0 + rr) * D_ + k0 + c] = __float2bfloat16(t[rr][c]);
  }
}

// ---- Stage B (fused GEMM+prep): 128x128 tile, 512 thr / 8 waves.
// A is read as fp32 (hs) and converted during staging (explicit LDS store,
// same address map as gl_lds16 -> conflict-free). Computes q-tile AND k-tile;
// epilogue emits q, kt=softplus(k), vT[b,h,d,p(s)] = q+k (key-swizzled per
// 64-chunk for attn's b128 PV reads).
__global__ __launch_bounds__(512, 2) void gemm_fused(
    const float* __restrict__ hs,
    const __hip_bfloat16* __restrict__ Wqt, const __hip_bfloat16* __restrict__ Wkt,
    const float* __restrict__ bq, const float* __restrict__ bk,
    __hip_bfloat16* __restrict__ q_out, __hip_bfloat16* __restrict__ kt_out,
    __hip_bfloat16* __restrict__ vT) {
  const int n0 = blockIdx.x * 128, m0 = blockIdx.y * 128;
  __shared__ __hip_bfloat16 As[2][128 * 32];
  __shared__ __hip_bfloat16 Bq[2][128 * 32];
  __shared__ __hip_bfloat16 Bk[2][128 * 32];
  const int tid = threadIdx.x, wid = tid >> 6, lane = tid & 63;
  const int wm = (wid >> 1) * 32, wn = (wid & 1) * 64;
  const int l15 = lane & 15, l4 = lane >> 4;
  const float4v zz = {0.f, 0.f, 0.f, 0.f};
  float4v accq[2][4], acck[2][4];
  for (int i = 0; i < 2; ++i)
    for (int j = 0; j < 4; ++j) { accq[i][j] = zz; acck[i][j] = zz; }
  const int lrow = wid * 16 + (lane >> 2);
  const int lk8 = (lane & 3) * 8;
  // preload chunk 0
  {
    const float* pa = hs + (size_t)(m0 + lrow) * D_ + lk8;
    const float4v a0 = ((const float4v*)pa)[0], a1 = ((const float4v*)pa)[1];
    short8 s;
    for (int j = 0; j < 4; ++j) { s[j] = f2bs(a0[j]); s[4 + j] = f2bs(a1[j]); }
    *(short8*)(As[0] + wid * 512 + lane * 8) = s;
    gl_lds16(Wqt + (size_t)(n0 + lrow) * D_ + lk8, Bq[0] + wid * 512);
    gl_lds16(Wkt + (size_t)(n0 + lrow) * D_ + lk8, Bk[0] + wid * 512);
  }
  int p = 0;
  for (int kb = 0; kb < 32; ++kb) {
    __syncthreads();  // buf[p] staged (vm+lgkm drained); prev frag reads done
    if (kb < 31) {
      const int kc = (kb + 1) * 32 + lk8;
      gl_lds16(Wqt + (size_t)(n0 + lrow) * D_ + kc, Bq[p ^ 1] + wid * 512);
      gl_lds16(Wkt + (size_t)(n0 + lrow) * D_ + kc, Bk[p ^ 1] + wid * 512);
      const float* pa = hs + (size_t)(m0 + lrow) * D_ + kc;
      const float4v a0 = ((const float4v*)pa)[0], a1 = ((const float4v*)pa)[1];
      short8 s;
      for (int j = 0; j < 4; ++j) { s[j] = f2bs(a0[j]); s[4 + j] = f2bs(a1[j]); }
      *(short8*)(As[p ^ 1] + wid * 512 + lane * 8) = s;
    }
    short8 af[2], bfq[4], bfk[4];
    const int fo = l4 * 8;
    for (int rt = 0; rt < 2; ++rt)
      af[rt] = *(const short8*)(As[p] + (wm + rt * 16 + l15) * 32 + fo);
    for (int ct = 0; ct < 4; ++ct) {
      bfq[ct] = *(const short8*)(Bq[p] + (wn + ct * 16 + l15) * 32 + fo);
      bfk[ct] = *(const short8*)(Bk[p] + (wn + ct * 16 + l15) * 32 + fo);
    }
    for (int rt = 0; rt < 2; ++rt)
      for (int ct = 0; ct < 4; ++ct) {
        accq[rt][ct] = mfma32(af[rt], bfq[ct], accq[rt][ct]);
        acck[rt][ct] = mfma32(af[rt], bfk[ct], acck[rt][ct]);
      }
    p ^= 1;
  }
  float bvq[4], bvk[4];
  for (int ct = 0; ct < 4; ++ct) {
    bvq[ct] = bq[n0 + wn + ct * 16 + l15];
    bvk[ct] = bk[n0 + wn + ct * 16 + l15];
  }
  for (int rt = 0; rt < 2; ++rt)
    for (int ct = 0; ct < 4; ++ct) {
      const int col = n0 + wn + ct * 16 + l15;
      const int h = col >> 6, d = col & 63;
      const int rowb = m0 + wm + rt * 16 + l4 * 4;
      short4v vv;
      for (int r = 0; r < 4; ++r) {
        const int row = rowb + r;
        const float qv = accq[rt][ct][r] + bvq[ct];
        const float kv = acck[rt][ct][r] + bvk[ct];
        const float sp = fmaxf(kv, 0.f) + __logf(1.f + __expf(-fabsf(kv)));
        q_out[(size_t)row * D_ + col] = __float2bfloat16(qv);
        kt_out[(size_t)row * D_ + col] = __float2bfloat16(sp);
        vv[r] = f2bs(qv + kv);
      }
      const int b = rowb >> 11, s = rowb & 2047;
      // key swizzle p(k) within 64-chunk; s%4==0 -> 4 consecutive stay together
      const int sw = (s & ~63) | (((s >> 4) & 3) << 2) | (((s >> 2) & 3) << 4);
      *(short4v*)(vT + ((size_t)(b * H_ + h) * HD_ + d) * S_ + sw) = vv;
    }
}

// ------- Stage D: flash attention — XCD-pinned, 128-key chunks (r15, 56 µs) ----
__global__ __launch_bounds__(256, 2) void attn(
    const __hip_bfloat16* __restrict__ qb, const __hip_bfloat16* __restrict__ ktb,
    const __hip_bfloat16* __restrict__ vT, const int* __restrict__ mask,
    float* __restrict__ out) {
  // buffer: kt0[4096] kt1[4096] v0[4096] v1[4096] shorts; 2 bufs = 65536 B
  __shared__ short smem[32768];
  const int id = blockIdx.x;
  const int xcd = id & 7;
  const int rest = id >> 3;              // 0..63
  const int q0 = (rest & 15) * 128;      // q-tile
  const int hb = (rest >> 4) * 8 + xcd;  // 0..31
  const int h = hb >> 1, b = hb & 1;
  const int tid = threadIdx.x, wid = tid >> 6, lane = tid & 63;
  const int l15 = lane & 15, l4 = lane >> 4;
  const __hip_bfloat16* qh = qb + (size_t)b * S_ * D_ + h * HD_;
  const __hip_bfloat16* kh = ktb + (size_t)b * S_ * D_ + h * HD_;
  const __hip_bfloat16* vh = vT + (size_t)(b * H_ + h) * HD_ * S_;
  // staging map: row=tid>>2 (0..63), two 16B blocks b0=(tid&3), b0+4
  const int srow = tid >> 2;
  const int b0 = tid & 3;
  const int sh = srow & 7;
  const int w0 = srow * 64 + ((b0 ^ sh) * 8);
  const int w1 = srow * 64 + (((b0 + 4) ^ sh) * 8);

  // q B-fragments for tiles A,B; mask*scale*log2e folded in
  const int qlA = wid * 32 + l15, qlB = qlA + 16;
  const int qrA = q0 + qlA, qrB = q0 + qlB;
  const float SC = 0.125f * 1.44269504f;
  const float mqA = (mask[b * S_ + qrA] != 0) ? SC : 0.f;
  const float mqB = (mask[b * S_ + qrB] != 0) ? SC : 0.f;
  const short8 rA0 = *(const short8*)(qh + (size_t)qrA * D_ + l4 * 8);
  const short8 rA1 = *(const short8*)(qh + (size_t)qrA * D_ + 32 + l4 * 8);
  const short8 rB0 = *(const short8*)(qh + (size_t)qrB * D_ + l4 * 8);
  const short8 rB1 = *(const short8*)(qh + (size_t)qrB * D_ + 32 + l4 * 8);
  short8 bqA0, bqA1, bqB0, bqB1;
  for (int j = 0; j < 8; ++j) {
    bqA0[j] = f2bs(bs2f(rA0[j]) * mqA);
    bqA1[j] = f2bs(bs2f(rA1[j]) * mqA);
    bqB0[j] = f2bs(bs2f(rB0[j]) * mqB);
    bqB1[j] = f2bs(bs2f(rB1[j]) * mqB);
  }

  // fragment read offsets (XOR-swizzled)
  const int lsh = l15 & 7;
  const int ak0off = l15 * 64 + ((l4 ^ lsh) * 8);          // + u*4096 + t*1024
  const int ak1off = l15 * 64 + (((l4 + 4) ^ lsh) * 8);
  const int vb0off = ((2 * l4) ^ lsh) * 8;                 // + 8192 + u*4096 + row*64
  const int vb1off = ((2 * l4 + 1) ^ lsh) * 8;

  const float4v zz = {0.f, 0.f, 0.f, 0.f};
  float4v oaccA[4] = {zz, zz, zz, zz};
  float4v oaccB[4] = {zz, zz, zz, zz};
  float lsumA = 0.f, lsumB = 0.f;

  // prefetch chunk 0 (two 64-key subchunks)
  short8 gk0[2], gk1[2], gv0[2], gv1[2];
#pragma unroll
  for (int u = 0; u < 2; ++u) {
    gk0[u] = *(const short8*)(kh + (size_t)(u * 64 + srow) * D_ + b0 * 8);
    gk1[u] = *(const short8*)(kh + (size_t)(u * 64 + srow) * D_ + b0 * 8 + 32);
    gv0[u] = *(const short8*)(vh + (size_t)srow * S_ + u * 64 + b0 * 8);
    gv1[u] = *(const short8*)(vh + (size_t)srow * S_ + u * 64 + b0 * 8 + 32);
  }

  int p = 0;
  for (int c = 0; c < 16; ++c) {
    short* bufp = smem + p * 16384;
#pragma unroll
    for (int u = 0; u < 2; ++u) {
      *(short8*)(bufp + u * 4096 + w0) = gk0[u];
      *(short8*)(bufp + u * 4096 + w1) = gk1[u];
      *(short8*)(bufp + 8192 + u * 4096 + w0) = gv0[u];
      *(short8*)(bufp + 8192 + u * 4096 + w1) = gv1[u];
    }
    __syncthreads();
    if (c < 15) {
      const int kb = (c + 1) * 128;
#pragma unroll
      for (int u = 0; u < 2; ++u) {
        gk0[u] = *(const short8*)(kh + (size_t)(kb + u * 64 + srow) * D_ + b0 * 8);
        gk1[u] = *(const short8*)(kh + (size_t)(kb + u * 64 + srow) * D_ + b0 * 8 + 32);
        gv0[u] = *(const short8*)(vh + (size_t)srow * S_ + kb + u * 64 + b0 * 8);
        gv1[u] = *(const short8*)(vh + (size_t)srow * S_ + kb + u * 64 + b0 * 8 + 32);
      }
    }
#pragma unroll
    for (int u = 0; u < 2; ++u) {  // 64-key subchunk
      const short* kbase = bufp + u * 4096;
      const short* vbase = bufp + 8192 + u * 4096;
      // ---- phase 1: QK for 4 key-tiles -> P fragments (exp2 domain) ----
      short4v pA[4], pB[4];
#pragma unroll
      for (int t = 0; t < 4; ++t) {
        const short8 ak0 = *(const short8*)(kbase + t * 1024 + ak0off);
        const short8 ak1 = *(const short8*)(kbase + t * 1024 + ak1off);
        float4v cA = zz, cB = zz;
        cA = mfma32(ak0, bqA0, cA);
        cA = mfma32(ak1, bqA1, cA);
        cB = mfma32(ak0, bqB0, cB);
        cB = mfma32(ak1, bqB1, cB);
        float eA[4], eB[4];
#pragma unroll
        for (int r = 0; r < 4; ++r) {
          eA[r] = __builtin_amdgcn_exp2f(cA[r]); lsumA += eA[r];
          eB[r] = __builtin_amdgcn_exp2f(cB[r]); lsumB += eB[r];
        }
        pA[t] = pk4(eA[0], eA[1], eA[2], eA[3]);
        pB[t] = pk4(eB[0], eB[1], eB[2], eB[3]);
      }
      // ---- phase 2: PV; 2x b128 per dt cover all 4 key-tiles (swizzled v) ----
#pragma unroll
      for (int dt = 0; dt < 4; ++dt) {
        const int rb = (dt * 16 + l15) * 64;
        const short8 av0 = *(const short8*)(vbase + rb + vb0off);
        const short8 av1 = *(const short8*)(vbase + rb + vb1off);
        const short4v a0 = {av0[0], av0[1], av0[2], av0[3]};
        const short4v a1 = {av0[4], av0[5], av0[6], av0[7]};
        const short4v a2 = {av1[0], av1[1], av1[2], av1[3]};
        const short4v a3 = {av1[4], av1[5], av1[6], av1[7]};
        oaccA[dt] = mfma16(a0, pA[0], oaccA[dt]);
        oaccB[dt] = mfma16(a0, pB[0], oaccB[dt]);
        oaccA[dt] = mfma16(a1, pA[1], oaccA[dt]);
        oaccB[dt] = mfma16(a1, pB[1], oaccB[dt]);
        oaccA[dt] = mfma16(a2, pA[2], oaccA[dt]);
        oaccB[dt] = mfma16(a2, pB[2], oaccB[dt]);
        oaccA[dt] = mfma16(a3, pA[3], oaccA[dt]);
        oaccB[dt] = mfma16(a3, pB[3], oaccB[dt]);
      }
    }
    p ^= 1;
  }
  // ---- epilogue: quad-reduce l; LDS transpose for coalesced stores ----
  float lA = lsumA + __shfl_xor(lsumA, 16); lA += __shfl_xor(lA, 32);
  float lB = lsumB + __shfl_xor(lsumB, 16); lB += __shfl_xor(lB, 32);
  __syncthreads();
  float* mbuf = (float*)smem;            // [128][68]
  float* mlb = (float*)smem + 128 * 68;  // [128]
#pragma unroll
  for (int dt = 0; dt < 4; ++dt)
#pragma unroll
    for (int r = 0; r < 4; ++r) {
      mbuf[qlA * 68 + dt * 16 + l4 * 4 + r] = oaccA[dt][r];
      mbuf[qlB * 68 + dt * 16 + l4 * 4 + r] = oaccB[dt][r];
    }
  if (l4 == 0) { mlb[qlA] = lA; mlb[qlB] = lB; }
  __syncthreads();
  const int qq = tid >> 1;
  const int dg = (tid & 1) * 32;
  const float li = 1.f / mlb[qq];
  float* orow = out + (size_t)(b * S_ + q0 + qq) * D_ + h * HD_ + dg;
#pragma unroll
  for (int i = 0; i < 8; ++i) {
    float4v v = *(const float4v*)&mbuf[qq * 68 + dg + i * 4];
#pragma unroll
    for (int r = 0; r < 4; ++r) v[r] *= li;
    *(float4v*)(orow + i * 4) = v;
  }
}

extern "C" void kernel_launch(void* const* d_in, const int* in_sizes, int n_in,
                              void* d_out, int out_size, void* d_ws, size_t ws_size,
                              hipStream_t stream) {
  const float* hs = (const float*)d_in[0];
  const int* mask = (const int*)d_in[1];
  const float* Wq = (const float*)d_in[2];
  const float* bq = (const float*)d_in[3];
  const float* Wk = (const float*)d_in[4];
  const float* bk = (const float*)d_in[5];
  float* out = (float*)d_out;
  char* ws = (char*)d_ws;
  const size_t MB = 1u << 20;
  __hip_bfloat16* q_b = (__hip_bfloat16*)(ws + 0 * MB);   // [B,S,D] bf16, 8MB
  __hip_bfloat16* k_b = (__hip_bfloat16*)(ws + 8 * MB);   // softplus(k), 8MB
  __hip_bfloat16* vT  = (__hip_bfloat16*)(ws + 16 * MB);  // [B,H,HD,S] key-swizzled, 8MB
  __hip_bfloat16* Wqt = (__hip_bfloat16*)(ws + 24 * MB);  // 2MB
  __hip_bfloat16* Wkt = (__hip_bfloat16*)(ws + 26 * MB);  // 2MB

  pre<<<dim3(16, 16, 2), 256, 0, stream>>>(Wq, Wk, Wqt, Wkt);
  gemm_fused<<<dim3(8, 32), 512, 0, stream>>>(hs, Wqt, Wkt, bq, bk, q_b, k_b, vT);
  attn<<<dim3(512), 256, 0, stream>>>(q_b, k_b, vT, mask, out);
}

// Round 19
// 164.766 us; speedup vs baseline: 2.7241x; 1.0129x over previous
//
#include <hip/hip_runtime.h>
#include <hip/hip_bf16.h>

#define B_ 2
#define S_ 2048
#define D_ 1024
#define H_ 16
#define HD_ 64

typedef __attribute__((ext_vector_type(8))) short short8;
typedef __attribute__((ext_vector_type(4))) short short4v;
typedef __attribute__((ext_vector_type(4))) float float4v;

typedef const __attribute__((address_space(1))) void* gas_ptr;
typedef __attribute__((address_space(3))) void* las_ptr;

static __device__ inline void gl_lds16(const void* g, void* l) {
  __builtin_amdgcn_global_load_lds((gas_ptr)g, (las_ptr)l, 16, 0, 0);
}

static __device__ inline float b2f(__hip_bfloat16 h) { return __bfloat162float(h); }

static __device__ inline short f2bs(float x) {
  __hip_bfloat16 h = __float2bfloat16(x);
  union { __hip_bfloat16 h; short s; } u; u.h = h; return u.s;
}
static __device__ inline float bs2f(short s) {
  union { short s; __hip_bfloat16 h; } u; u.s = s; return __bfloat162float(u.h);
}
// packed f32x4 -> bf16x4 (v_cvt_pk_bf16_f32 x2)
static __device__ inline short4v pk4(float a, float b, float c, float d) {
  union { __hip_bfloat162 h[2]; short4v s; } u;
  u.h[0] = __float22bfloat162_rn(float2{a, b});
  u.h[1] = __float22bfloat162_rn(float2{c, d});
  return u.s;
}

static __device__ inline float4v mfma32(short8 a, short8 b, float4v c) {
  return __builtin_amdgcn_mfma_f32_16x16x32_bf16(a, b, c, 0, 0, 0);
}
// v_mfma_f32_16x16x16_bf16 — "_1k" builtin, present on gfx950.
static __device__ inline float4v mfma16(short4v a, short4v b, float4v c) {
  return __builtin_amdgcn_mfma_f32_16x16x16bf16_1k(a, b, c, 0, 0, 0);
}

// ------- Stage A: W fp32 [k][n] -> Wt bf16 [n][k] -------
__global__ __launch_bounds__(256) void pre(
    const float* __restrict__ Wq, const float* __restrict__ Wk,
    __hip_bfloat16* __restrict__ Wqt, __hip_bfloat16* __restrict__ Wkt) {
  const float* W = blockIdx.z ? Wk : Wq;
  __hip_bfloat16* Wt = blockIdx.z ? Wkt : Wqt;
  __shared__ float t[64][65];
  const int n0 = blockIdx.x * 64, k0 = blockIdx.y * 64;
  const int c = threadIdx.x & 63, r0 = threadIdx.x >> 6;
  for (int i = 0; i < 16; ++i) {
    const int r = i * 4 + r0;
    t[c][r] = W[(size_t)(k0 + r) * D_ + n0 + c];
  }
  __syncthreads();
  for (int i = 0; i < 16; ++i) {
    const int rr = i * 4 + r0;
    Wt[(size_t)(n0 + rr) * D_ + k0 + c] = __float2bfloat16(t[rr][c]);
  }
}

// ---- Stage B (fused GEMM+prep): 128x128 tile, 512 thr / 8 waves, XCD-PINNED.
// Flat grid 256: xcd=id&7 owns m-tiles {4*xcd..4*xcd+3} x all 8 n-blocks ->
// A-tile slices + W slices stay L2-resident per XCD (A fetched ~once chip-wide
// vs 8x with the naive (n,m) grid). A read as fp32 (hs), converted during
// staging. Epilogue emits q, kt=softplus(k), vT[b,h,d,p(s)]=q+k (key-swizzled
// per 64-chunk for attn's b128 PV reads).
__global__ __launch_bounds__(512, 2) void gemm_fused(
    const float* __restrict__ hs,
    const __hip_bfloat16* __restrict__ Wqt, const __hip_bfloat16* __restrict__ Wkt,
    const float* __restrict__ bq, const float* __restrict__ bk,
    __hip_bfloat16* __restrict__ q_out, __hip_bfloat16* __restrict__ kt_out,
    __hip_bfloat16* __restrict__ vT) {
  const int id = blockIdx.x;
  const int mt = (id & 7) * 4 + ((id >> 3) & 3);  // m-tile 0..31, pinned by xcd
  const int nt = id >> 5;                          // n-block 0..7
  const int n0 = nt * 128, m0 = mt * 128;
  __shared__ __hip_bfloat16 As[2][128 * 32];
  __shared__ __hip_bfloat16 Bq[2][128 * 32];
  __shared__ __hip_bfloat16 Bk[2][128 * 32];
  const int tid = threadIdx.x, wid = tid >> 6, lane = tid & 63;
  const int wm = (wid >> 1) * 32, wn = (wid & 1) * 64;
  const int l15 = lane & 15, l4 = lane >> 4;
  const float4v zz = {0.f, 0.f, 0.f, 0.f};
  float4v accq[2][4], acck[2][4];
  for (int i = 0; i < 2; ++i)
    for (int j = 0; j < 4; ++j) { accq[i][j] = zz; acck[i][j] = zz; }
  const int lrow = wid * 16 + (lane >> 2);
  const int lk8 = (lane & 3) * 8;
  // preload chunk 0
  {
    const float* pa = hs + (size_t)(m0 + lrow) * D_ + lk8;
    const float4v a0 = ((const float4v*)pa)[0], a1 = ((const float4v*)pa)[1];
    short8 s;
    for (int j = 0; j < 4; ++j) { s[j] = f2bs(a0[j]); s[4 + j] = f2bs(a1[j]); }
    *(short8*)(As[0] + wid * 512 + lane * 8) = s;
    gl_lds16(Wqt + (size_t)(n0 + lrow) * D_ + lk8, Bq[0] + wid * 512);
    gl_lds16(Wkt + (size_t)(n0 + lrow) * D_ + lk8, Bk[0] + wid * 512);
  }
  int p = 0;
  for (int kb = 0; kb < 32; ++kb) {
    __syncthreads();  // buf[p] staged (vm+lgkm drained); prev frag reads done
    if (kb < 31) {
      const int kc = (kb + 1) * 32 + lk8;
      gl_lds16(Wqt + (size_t)(n0 + lrow) * D_ + kc, Bq[p ^ 1] + wid * 512);
      gl_lds16(Wkt + (size_t)(n0 + lrow) * D_ + kc, Bk[p ^ 1] + wid * 512);
      const float* pa = hs + (size_t)(m0 + lrow) * D_ + kc;
      const float4v a0 = ((const float4v*)pa)[0], a1 = ((const float4v*)pa)[1];
      short8 s;
      for (int j = 0; j < 4; ++j) { s[j] = f2bs(a0[j]); s[4 + j] = f2bs(a1[j]); }
      *(short8*)(As[p ^ 1] + wid * 512 + lane * 8) = s;
    }
    short8 af[2], bfq[4], bfk[4];
    const int fo = l4 * 8;
    for (int rt = 0; rt < 2; ++rt)
      af[rt] = *(const short8*)(As[p] + (wm + rt * 16 + l15) * 32 + fo);
    for (int ct = 0; ct < 4; ++ct) {
      bfq[ct] = *(const short8*)(Bq[p] + (wn + ct * 16 + l15) * 32 + fo);
      bfk[ct] = *(const short8*)(Bk[p] + (wn + ct * 16 + l15) * 32 + fo);
    }
    for (int rt = 0; rt < 2; ++rt)
      for (int ct = 0; ct < 4; ++ct) {
        accq[rt][ct] = mfma32(af[rt], bfq[ct], accq[rt][ct]);
        acck[rt][ct] = mfma32(af[rt], bfk[ct], acck[rt][ct]);
      }
    p ^= 1;
  }
  float bvq[4], bvk[4];
  for (int ct = 0; ct < 4; ++ct) {
    bvq[ct] = bq[n0 + wn + ct * 16 + l15];
    bvk[ct] = bk[n0 + wn + ct * 16 + l15];
  }
  for (int rt = 0; rt < 2; ++rt)
    for (int ct = 0; ct < 4; ++ct) {
      const int col = n0 + wn + ct * 16 + l15;
      const int h = col >> 6, d = col & 63;
      const int rowb = m0 + wm + rt * 16 + l4 * 4;
      short4v vv;
      for (int r = 0; r < 4; ++r) {
        const int row = rowb + r;
        const float qv = accq[rt][ct][r] + bvq[ct];
        const float kv = acck[rt][ct][r] + bvk[ct];
        const float sp = fmaxf(kv, 0.f) + __logf(1.f + __expf(-fabsf(kv)));
        q_out[(size_t)row * D_ + col] = __float2bfloat16(qv);
        kt_out[(size_t)row * D_ + col] = __float2bfloat16(sp);
        vv[r] = f2bs(qv + kv);
      }
      const int b = rowb >> 11, s = rowb & 2047;
      // key swizzle p(k) within 64-chunk; s%4==0 -> 4 consecutive stay together
      const int sw = (s & ~63) | (((s >> 4) & 3) << 2) | (((s >> 2) & 3) << 4);
      *(short4v*)(vT + ((size_t)(b * H_ + h) * HD_ + d) * S_ + sw) = vv;
    }
}

// ------- Stage D: flash attention — XCD-pinned, 128-key chunks (r15, 55 µs) ----
__global__ __launch_bounds__(256, 2) void attn(
    const __hip_bfloat16* __restrict__ qb, const __hip_bfloat16* __restrict__ ktb,
    const __hip_bfloat16* __restrict__ vT, const int* __restrict__ mask,
    float* __restrict__ out) {
  // buffer: kt0[4096] kt1[4096] v0[4096] v1[4096] shorts; 2 bufs = 65536 B
  __shared__ short smem[32768];
  const int id = blockIdx.x;
  const int xcd = id & 7;
  const int rest = id >> 3;              // 0..63
  const int q0 = (rest & 15) * 128;      // q-tile
  const int hb = (rest >> 4) * 8 + xcd;  // 0..31
  const int h = hb >> 1, b = hb & 1;
  const int tid = threadIdx.x, wid = tid >> 6, lane = tid & 63;
  const int l15 = lane & 15, l4 = lane >> 4;
  const __hip_bfloat16* qh = qb + (size_t)b * S_ * D_ + h * HD_;
  const __hip_bfloat16* kh = ktb + (size_t)b * S_ * D_ + h * HD_;
  const __hip_bfloat16* vh = vT + (size_t)(b * H_ + h) * HD_ * S_;
  // staging map: row=tid>>2 (0..63), two 16B blocks b0=(tid&3), b0+4
  const int srow = tid >> 2;
  const int b0 = tid & 3;
  const int sh = srow & 7;
  const int w0 = srow * 64 + ((b0 ^ sh) * 8);
  const int w1 = srow * 64 + (((b0 + 4) ^ sh) * 8);

  // q B-fragments for tiles A,B; mask*scale*log2e folded in
  const int qlA = wid * 32 + l15, qlB = qlA + 16;
  const int qrA = q0 + qlA, qrB = q0 + qlB;
  const float SC = 0.125f * 1.44269504f;
  const float mqA = (mask[b * S_ + qrA] != 0) ? SC : 0.f;
  const float mqB = (mask[b * S_ + qrB] != 0) ? SC : 0.f;
  const short8 rA0 = *(const short8*)(qh + (size_t)qrA * D_ + l4 * 8);
  const short8 rA1 = *(const short8*)(qh + (size_t)qrA * D_ + 32 + l4 * 8);
  const short8 rB0 = *(const short8*)(qh + (size_t)qrB * D_ + l4 * 8);
  const short8 rB1 = *(const short8*)(qh + (size_t)qrB * D_ + 32 + l4 * 8);
  short8 bqA0, bqA1, bqB0, bqB1;
  for (int j = 0; j < 8; ++j) {
    bqA0[j] = f2bs(bs2f(rA0[j]) * mqA);
    bqA1[j] = f2bs(bs2f(rA1[j]) * mqA);
    bqB0[j] = f2bs(bs2f(rB0[j]) * mqB);
    bqB1[j] = f2bs(bs2f(rB1[j]) * mqB);
  }

  // fragment read offsets (XOR-swizzled)
  const int lsh = l15 & 7;
  const int ak0off = l15 * 64 + ((l4 ^ lsh) * 8);          // + u*4096 + t*1024
  const int ak1off = l15 * 64 + (((l4 + 4) ^ lsh) * 8);
  const int vb0off = ((2 * l4) ^ lsh) * 8;                 // + 8192 + u*4096 + row*64
  const int vb1off = ((2 * l4 + 1) ^ lsh) * 8;

  const float4v zz = {0.f, 0.f, 0.f, 0.f};
  float4v oaccA[4] = {zz, zz, zz, zz};
  float4v oaccB[4] = {zz, zz, zz, zz};
  float lsumA = 0.f, lsumB = 0.f;

  // prefetch chunk 0 (two 64-key subchunks)
  short8 gk0[2], gk1[2], gv0[2], gv1[2];
#pragma unroll
  for (int u = 0; u < 2; ++u) {
    gk0[u] = *(const short8*)(kh + (size_t)(u * 64 + srow) * D_ + b0 * 8);
    gk1[u] = *(const short8*)(kh + (size_t)(u * 64 + srow) * D_ + b0 * 8 + 32);
    gv0[u] = *(const short8*)(vh + (size_t)srow * S_ + u * 64 + b0 * 8);
    gv1[u] = *(const short8*)(vh + (size_t)srow * S_ + u * 64 + b0 * 8 + 32);
  }

  int p = 0;
  for (int c = 0; c < 16; ++c) {
    short* bufp = smem + p * 16384;
#pragma unroll
    for (int u = 0; u < 2; ++u) {
      *(short8*)(bufp + u * 4096 + w0) = gk0[u];
      *(short8*)(bufp + u * 4096 + w1) = gk1[u];
      *(short8*)(bufp + 8192 + u * 4096 + w0) = gv0[u];
      *(short8*)(bufp + 8192 + u * 4096 + w1) = gv1[u];
    }
    __syncthreads();
    if (c < 15) {
      const int kb = (c + 1) * 128;
#pragma unroll
      for (int u = 0; u < 2; ++u) {
        gk0[u] = *(const short8*)(kh + (size_t)(kb + u * 64 + srow) * D_ + b0 * 8);
        gk1[u] = *(const short8*)(kh + (size_t)(kb + u * 64 + srow) * D_ + b0 * 8 + 32);
        gv0[u] = *(const short8*)(vh + (size_t)srow * S_ + kb + u * 64 + b0 * 8);
        gv1[u] = *(const short8*)(vh + (size_t)srow * S_ + kb + u * 64 + b0 * 8 + 32);
      }
    }
#pragma unroll
    for (int u = 0; u < 2; ++u) {  // 64-key subchunk
      const short* kbase = bufp + u * 4096;
      const short* vbase = bufp + 8192 + u * 4096;
      // ---- phase 1: QK for 4 key-tiles -> P fragments (exp2 domain) ----
      short4v pA[4], pB[4];
#pragma unroll
      for (int t = 0; t < 4; ++t) {
        const short8 ak0 = *(const short8*)(kbase + t * 1024 + ak0off);
        const short8 ak1 = *(const short8*)(kbase + t * 1024 + ak1off);
        float4v cA = zz, cB = zz;
        cA = mfma32(ak0, bqA0, cA);
        cA = mfma32(ak1, bqA1, cA);
        cB = mfma32(ak0, bqB0, cB);
        cB = mfma32(ak1, bqB1, cB);
        float eA[4], eB[4];
#pragma unroll
        for (int r = 0; r < 4; ++r) {
          eA[r] = __builtin_amdgcn_exp2f(cA[r]); lsumA += eA[r];
          eB[r] = __builtin_amdgcn_exp2f(cB[r]); lsumB += eB[r];
        }
        pA[t] = pk4(eA[0], eA[1], eA[2], eA[3]);
        pB[t] = pk4(eB[0], eB[1], eB[2], eB[3]);
      }
      // ---- phase 2: PV; 2x b128 per dt cover all 4 key-tiles (swizzled v) ----
#pragma unroll
      for (int dt = 0; dt < 4; ++dt) {
        const int rb = (dt * 16 + l15) * 64;
        const short8 av0 = *(const short8*)(vbase + rb + vb0off);
        const short8 av1 = *(const short8*)(vbase + rb + vb1off);
        const short4v a0 = {av0[0], av0[1], av0[2], av0[3]};
        const short4v a1 = {av0[4], av0[5], av0[6], av0[7]};
        const short4v a2 = {av1[0], av1[1], av1[2], av1[3]};
        const short4v a3 = {av1[4], av1[5], av1[6], av1[7]};
        oaccA[dt] = mfma16(a0, pA[0], oaccA[dt]);
        oaccB[dt] = mfma16(a0, pB[0], oaccB[dt]);
        oaccA[dt] = mfma16(a1, pA[1], oaccA[dt]);
        oaccB[dt] = mfma16(a1, pB[1], oaccB[dt]);
        oaccA[dt] = mfma16(a2, pA[2], oaccA[dt]);
        oaccB[dt] = mfma16(a2, pB[2], oaccB[dt]);
        oaccA[dt] = mfma16(a3, pA[3], oaccA[dt]);
        oaccB[dt] = mfma16(a3, pB[3], oaccB[dt]);
      }
    }
    p ^= 1;
  }
  // ---- epilogue: quad-reduce l; LDS transpose for coalesced stores ----
  float lA = lsumA + __shfl_xor(lsumA, 16); lA += __shfl_xor(lA, 32);
  float lB = lsumB + __shfl_xor(lsumB, 16); lB += __shfl_xor(lB, 32);
  __syncthreads();
  float* mbuf = (float*)smem;            // [128][68]
  float* mlb = (float*)smem + 128 * 68;  // [128]
#pragma unroll
  for (int dt = 0; dt < 4; ++dt)
#pragma unroll
    for (int r = 0; r < 4; ++r) {
      mbuf[qlA * 68 + dt * 16 + l4 * 4 + r] = oaccA[dt][r];
      mbuf[qlB * 68 + dt * 16 + l4 * 4 + r] = oaccB[dt][r];
    }
  if (l4 == 0) { mlb[qlA] = lA; mlb[qlB] = lB; }
  __syncthreads();
  const int qq = tid >> 1;
  const int dg = (tid & 1) * 32;
  const float li = 1.f / mlb[qq];
  float* orow = out + (size_t)(b * S_ + q0 + qq) * D_ + h * HD_ + dg;
#pragma unroll
  for (int i = 0; i < 8; ++i) {
    float4v v = *(const float4v*)&mbuf[qq * 68 + dg + i * 4];
#pragma unroll
    for (int r = 0; r < 4; ++r) v[r] *= li;
    *(float4v*)(orow + i * 4) = v;
  }
}

extern "C" void kernel_launch(void* const* d_in, const int* in_sizes, int n_in,
                              void* d_out, int out_size, void* d_ws, size_t ws_size,
                              hipStream_t stream) {
  const float* hs = (const float*)d_in[0];
  const int* mask = (const int*)d_in[1];
  const float* Wq = (const float*)d_in[2];
  const float* bq = (const float*)d_in[3];
  const float* Wk = (const float*)d_in[4];
  const float* bk = (const float*)d_in[5];
  float* out = (float*)d_out;
  char* ws = (char*)d_ws;
  const size_t MB = 1u << 20;
  __hip_bfloat16* q_b = (__hip_bfloat16*)(ws + 0 * MB);   // [B,S,D] bf16, 8MB
  __hip_bfloat16* k_b = (__hip_bfloat16*)(ws + 8 * MB);   // softplus(k), 8MB
  __hip_bfloat16* vT  = (__hip_bfloat16*)(ws + 16 * MB);  // [B,H,HD,S] key-swizzled, 8MB
  __hip_bfloat16* Wqt = (__hip_bfloat16*)(ws + 24 * MB);  // 2MB
  __hip_bfloat16* Wkt = (__hip_bfloat16*)(ws + 26 * MB);  // 2MB

  pre<<<dim3(16, 16, 2), 256, 0, stream>>>(Wq, Wk, Wqt, Wkt);
  gemm_fused<<<dim3(256), 512, 0, stream>>>(hs, Wqt, Wkt, bq, bk, q_b, k_b, vT);
  attn<<<dim3(512), 256, 0, stream>>>(q_b, k_b, vT, mask, out);
}